// Round 2
// baseline (967.363 us; speedup 1.0000x reference)
//
#include <hip/hip_runtime.h>

// VQ codebook: z_e [32,64,64,64] f32 (B,C,W,H), emb [1024,64] f32.
// Outputs concat: quantized [32,64,64,64] f32, indices [131072] (as f32), vq_loss [1] f32.
//
// R2: k-split x4. Each point scanned by 4 threads (one wave per k-quarter),
// merged via LDS. Grid 512->2048 blocks => 8192 waves => ~6 waves/SIMD to hide
// the per-k scalar emb-row load latency. Inner-loop arithmetic identical to R1
// (which matched the np reference exactly).

#define CDIM   64
#define KCODES 1024
#define NPTS   131072      // 32*64*64
#define WH     4096        // 64*64
#define CWH    262144      // 64*4096
#define SPLIT  4
#define KPER   (KCODES / SPLIT)   // 256
#define NBLK   (NPTS / 64)        // 2048 blocks, 64 points each

// Kernel 0: E[k] = ||emb_k||^2
__global__ __launch_bounds__(256) void vq_esq(const float* __restrict__ emb,
                                              float* __restrict__ E) {
    int k = blockIdx.x * 256 + threadIdx.x;
    if (k >= KCODES) return;
    const float4* e4 = (const float4*)(emb + k * CDIM);
    float s = 0.f;
#pragma unroll
    for (int i = 0; i < CDIM / 4; ++i) {
        float4 v = e4[i];
        s = fmaf(v.x, v.x, s);
        s = fmaf(v.y, v.y, s);
        s = fmaf(v.z, v.z, s);
        s = fmaf(v.w, v.w, s);
    }
    E[k] = s;
}

// Kernel 1: 64 points per block, 4 k-splits (one per wave).
__global__ __launch_bounds__(256) void vq_main(const float* __restrict__ z_e,
                                               const float* __restrict__ emb,
                                               const float* __restrict__ E,
                                               float* __restrict__ out_q,
                                               float* __restrict__ out_idx,
                                               float* __restrict__ partials) {
    const int tid   = threadIdx.x;
    const int lane  = tid & 63;        // point within block
    const int split = tid >> 6;        // 0..3 == wave id (wave-uniform k range)
    const int n     = blockIdx.x * 64 + lane;
    const int b     = n >> 12;         // n / 4096
    const int wh    = n & 4095;

    // Load this point's 64 channels. Coalesced: fixed c, consecutive lanes ->
    // consecutive wh. The 4 waves of a block re-read the same 16KB -> L1 hits.
    const float* zp = z_e + (size_t)b * CWH + wh;
    float z[CDIM];
#pragma unroll
    for (int c = 0; c < CDIM; ++c) z[c] = zp[c * WH];

    // Scan this wave's quarter of the codebook. emb row address wave-uniform
    // -> scalar loads. Arithmetic identical to the exact-matching R1 kernel.
    float best  = 1e30f;
    int   bestk = 0;
    const int k0 = split * KPER;
    for (int k = k0; k < k0 + KPER; ++k) {
        const float* er = emb + k * CDIM;
        float d0 = 0.f, d1 = 0.f, d2 = 0.f, d3 = 0.f;
#pragma unroll
        for (int c = 0; c < CDIM; c += 4) {
            d0 = fmaf(z[c + 0], er[c + 0], d0);
            d1 = fmaf(z[c + 1], er[c + 1], d1);
            d2 = fmaf(z[c + 2], er[c + 2], d2);
            d3 = fmaf(z[c + 3], er[c + 3], d3);
        }
        float dot   = (d0 + d1) + (d2 + d3);
        float score = fmaf(-2.0f, dot, E[k]);
        if (score < best) { best = score; bestk = k; }   // first-min within split
    }

    // Merge the 4 split candidates per point. Ascending split order + strict <
    // == global first-min (jnp.argmin tie-break).
    __shared__ float s_best[SPLIT * 64];
    __shared__ int   s_bestk[SPLIT * 64];
    s_best[split * 64 + lane]  = best;
    s_bestk[split * 64 + lane] = bestk;
    __syncthreads();
    float mb = s_best[lane];
    int   mk = s_bestk[lane];
#pragma unroll
    for (int s = 1; s < SPLIT; ++s) {
        float v  = s_best[s * 64 + lane];
        int   kk = s_bestk[s * 64 + lane];
        if (v < mb) { mb = v; mk = kk; }
    }

    // Distributed writeback: each split writes 16 channels of this point's q,
    // and accumulates its share of the loss.
    const float* eb = emb + mk * CDIM;
    float* qp = out_q + (size_t)b * CWH + wh;
    const int c0 = split * (CDIM / SPLIT);
    float lsum = 0.f;
#pragma unroll
    for (int c = 0; c < CDIM / SPLIT; ++c) {
        float v = eb[c0 + c];
        qp[(size_t)(c0 + c) * WH] = v;
        float d = v - z[c0 + c];
        lsum = fmaf(d, d, lsum);
    }
    if (split == 0) out_idx[n] = (float)mk;

    // Deterministic block reduction of loss partial.
    __shared__ float red[256];
    red[tid] = lsum;
    __syncthreads();
    for (int s = 128; s > 0; s >>= 1) {
        if (tid < s) red[tid] += red[tid + s];
        __syncthreads();
    }
    if (tid == 0) partials[blockIdx.x] = red[0];
}

// Kernel 2: final deterministic reduction of 2048 partials -> loss.
__global__ __launch_bounds__(1024) void vq_loss_fin(const float* __restrict__ partials,
                                                    float* __restrict__ loss) {
    __shared__ float red[1024];
    int t = threadIdx.x;
    red[t] = partials[t] + partials[t + 1024];
    __syncthreads();
    for (int s = 512; s > 0; s >>= 1) {
        if (t < s) red[t] += red[t + s];
        __syncthreads();
    }
    if (t == 0) loss[0] = red[0] * (1.25f / 8388608.0f);  // (1+BETA)*mean
}

extern "C" void kernel_launch(void* const* d_in, const int* in_sizes, int n_in,
                              void* d_out, int out_size, void* d_ws, size_t ws_size,
                              hipStream_t stream) {
    const float* z_e = (const float*)d_in[0];
    const float* emb = (const float*)d_in[1];

    float* out      = (float*)d_out;
    float* out_q    = out;                       // 8388608 elems
    float* out_idx  = out + 8388608;             // 131072 elems (float-encoded ints)
    float* out_loss = out + 8388608 + 131072;    // 1 elem

    float* E        = (float*)d_ws;              // 1024 floats
    float* partials = E + KCODES;                // 2048 floats

    vq_esq<<<KCODES / 256, 256, 0, stream>>>(emb, E);
    vq_main<<<NBLK, 256, 0, stream>>>(z_e, emb, E, out_q, out_idx, partials);
    vq_loss_fin<<<1, 1024, 0, stream>>>(partials, out_loss);
}

// Round 3
// 300.478 us; speedup vs baseline: 3.2194x; 3.2194x over previous
//
#include <hip/hip_runtime.h>

// VQ codebook: z_e [32,64,64,64] f32 (B,C,W,H), emb [1024,64] f32.
// Outputs concat: quantized [32,64,64,64] f32, indices [131072] (as f32), vq_loss [1] f32.
//
// R3: k-split x4 via blockIdx.y (wave-uniform in the compiler's view -> the
// s_load_dwordx16 emb-row path survives; R2's threadIdx-derived split killed
// it, SGPR 96->32). 8192 waves => ~6-8 waves/SIMD hides scalar-load latency.
// Scan arithmetic bit-identical to R1 (absmax 0.0); merge = ascending-split
// strict-< == jnp.argmin first-min order.

#define CDIM   64
#define KCODES 1024
#define NPTS   131072      // 32*64*64
#define WH     4096        // 64*64
#define CWH    262144      // 64*4096
#define SPLIT  4
#define KPER   (KCODES / SPLIT)   // 256
#define NBLK   (NPTS / 256)       // 512 point-blocks

// Kernel 0: E[k] = ||emb_k||^2
__global__ __launch_bounds__(256) void vq_esq(const float* __restrict__ emb,
                                              float* __restrict__ E) {
    int k = blockIdx.x * 256 + threadIdx.x;
    if (k >= KCODES) return;
    const float4* e4 = (const float4*)(emb + k * CDIM);
    float s = 0.f;
#pragma unroll
    for (int i = 0; i < CDIM / 4; ++i) {
        float4 v = e4[i];
        s = fmaf(v.x, v.x, s);
        s = fmaf(v.y, v.y, s);
        s = fmaf(v.z, v.z, s);
        s = fmaf(v.w, v.w, s);
    }
    E[k] = s;
}

// Kernel 1: scan. blockIdx.x = point block (256 pts), blockIdx.y = k-split.
// Emits per-split (best, bestk) candidates.
__global__ __launch_bounds__(256) void vq_scan(const float* __restrict__ z_e,
                                               const float* __restrict__ emb,
                                               const float* __restrict__ E,
                                               float* __restrict__ cand_best,
                                               int* __restrict__ cand_k) {
    const int tid = threadIdx.x;
    const int n   = blockIdx.x * 256 + tid;
    const int b   = n >> 12;       // block spans one b (256 | 4096)
    const int wh  = n & 4095;
    const int k0  = blockIdx.y * KPER;   // SGPR -> wave-uniform -> scalar loads

    // Point's 64 channels into VGPRs. Coalesced: fixed c, consecutive lanes.
    const float* zp = z_e + (size_t)b * CWH + wh;
    float z[CDIM];
#pragma unroll
    for (int c = 0; c < CDIM; ++c) z[c] = zp[c * WH];

    // Scan this split's quarter. Arithmetic identical to R1's exact match.
    float best  = 1e30f;
    int   bestk = 0;
    for (int k = k0; k < k0 + KPER; ++k) {
        const float* er = emb + k * CDIM;
        float d0 = 0.f, d1 = 0.f, d2 = 0.f, d3 = 0.f;
#pragma unroll
        for (int c = 0; c < CDIM; c += 4) {
            d0 = fmaf(z[c + 0], er[c + 0], d0);
            d1 = fmaf(z[c + 1], er[c + 1], d1);
            d2 = fmaf(z[c + 2], er[c + 2], d2);
            d3 = fmaf(z[c + 3], er[c + 3], d3);
        }
        float dot   = (d0 + d1) + (d2 + d3);
        float score = fmaf(-2.0f, dot, E[k]);
        if (score < best) { best = score; bestk = k; }   // first-min within split
    }

    cand_best[blockIdx.y * NPTS + n] = best;
    cand_k[blockIdx.y * NPTS + n]   = bestk;
}

// Kernel 2: merge candidates, gather winning code, write q/idx, loss partials.
__global__ __launch_bounds__(256) void vq_merge(const float* __restrict__ z_e,
                                                const float* __restrict__ emb,
                                                const float* __restrict__ cand_best,
                                                const int* __restrict__ cand_k,
                                                float* __restrict__ out_q,
                                                float* __restrict__ out_idx,
                                                float* __restrict__ partials) {
    const int tid = threadIdx.x;
    const int n   = blockIdx.x * 256 + tid;
    const int b   = n >> 12;
    const int wh  = n & 4095;

    // Ascending split order + strict < == global first-min (jnp.argmin).
    float mb = cand_best[n];
    int   mk = cand_k[n];
#pragma unroll
    for (int s = 1; s < SPLIT; ++s) {
        float v  = cand_best[s * NPTS + n];
        int   kk = cand_k[s * NPTS + n];
        if (v < mb) { mb = v; mk = kk; }
    }
    out_idx[n] = (float)mk;

    // Gather winning code row (L2-resident table), write q, accumulate loss
    // in the same c-order fmaf chain as R1.
    const float* eb = emb + mk * CDIM;
    const float* zp = z_e + (size_t)b * CWH + wh;
    float* qp = out_q + (size_t)b * CWH + wh;
    float lsum = 0.f;
#pragma unroll
    for (int c = 0; c < CDIM; ++c) {
        float ev = eb[c];
        qp[c * WH] = ev;
        float d = ev - zp[c * WH];
        lsum = fmaf(d, d, lsum);
    }

    __shared__ float red[256];
    red[tid] = lsum;
    __syncthreads();
    for (int s = 128; s > 0; s >>= 1) {
        if (tid < s) red[tid] += red[tid + s];
        __syncthreads();
    }
    if (tid == 0) partials[blockIdx.x] = red[0];
}

// Kernel 3: final deterministic reduction of 512 partials -> loss.
__global__ __launch_bounds__(512) void vq_loss_fin(const float* __restrict__ partials,
                                                   float* __restrict__ loss) {
    __shared__ float red[NBLK];
    int t = threadIdx.x;
    red[t] = partials[t];
    __syncthreads();
    for (int s = NBLK / 2; s > 0; s >>= 1) {
        if (t < s) red[t] += red[t + s];
        __syncthreads();
    }
    if (t == 0) loss[0] = red[0] * (1.25f / 8388608.0f);  // (1+BETA)*mean
}

extern "C" void kernel_launch(void* const* d_in, const int* in_sizes, int n_in,
                              void* d_out, int out_size, void* d_ws, size_t ws_size,
                              hipStream_t stream) {
    const float* z_e = (const float*)d_in[0];
    const float* emb = (const float*)d_in[1];

    float* out      = (float*)d_out;
    float* out_q    = out;                       // 8388608 elems
    float* out_idx  = out + 8388608;             // 131072 elems (float-encoded ints)
    float* out_loss = out + 8388608 + 131072;    // 1 elem

    float* E         = (float*)d_ws;                  // 1024 f32
    float* cand_best = E + KCODES;                    // SPLIT*NPTS f32
    int*   cand_k    = (int*)(cand_best + SPLIT * NPTS); // SPLIT*NPTS i32
    float* partials  = (float*)(cand_k + SPLIT * NPTS);  // 512 f32

    vq_esq<<<KCODES / 256, 256, 0, stream>>>(emb, E);
    dim3 grid_scan(NBLK, SPLIT);
    vq_scan<<<grid_scan, 256, 0, stream>>>(z_e, emb, E, cand_best, cand_k);
    vq_merge<<<NBLK, 256, 0, stream>>>(z_e, emb, cand_best, cand_k,
                                       out_q, out_idx, partials);
    vq_loss_fin<<<1, NBLK, 0, stream>>>(partials, out_loss);
}